// Round 7
// baseline (416.063 us; speedup 1.0000x reference)
//
#include <hip/hip_runtime.h>
#include <cstdint>
#include <cstddef>

#define NB 8192
// NINP=256, NHID=1024, NB_OUT=8, BS_OUT=128, ATT_OUT=512

typedef __attribute__((ext_vector_type(4))) float f32x4;
typedef __attribute__((ext_vector_type(8))) short bf16x8;

__device__ __forceinline__ float sigmoidf_(float x){ return 1.0f/(1.0f+expf(-x)); }

__device__ __forceinline__ unsigned short f2bf(float f){
    union { float f; unsigned u; } v; v.f = f;
    unsigned u = v.u;
    return (unsigned short)((u + 0x7fffu + ((u >> 16) & 1u)) >> 16);
}
__device__ __forceinline__ float bf2f(unsigned short b){
    union { unsigned u; float f; } v; v.u = ((unsigned)b) << 16;
    return v.f;
}
__device__ __forceinline__ void ld8f(const unsigned short* p, float* f){
    uint4 u = *(const uint4*)p;
    f[0]=bf2f(u.x&0xffff); f[1]=bf2f(u.x>>16);
    f[2]=bf2f(u.y&0xffff); f[3]=bf2f(u.y>>16);
    f[4]=bf2f(u.z&0xffff); f[5]=bf2f(u.z>>16);
    f[6]=bf2f(u.w&0xffff); f[7]=bf2f(u.w>>16);
}
#define MFMA16(a,b,c) __builtin_amdgcn_mfma_f32_16x16x32_bf16(a,b,c,0,0,0)

// ---------------------------------------------------------------------------
// prep_all: casts + weight transposes/permutations. One launch.
// Permutation (gate-interleave): orig col n in [0,384): g=n>>7, jj=n&127,
//   b2=jj>>6, c' = b2*192 + g*64 + (jj&63).
// ---------------------------------------------------------------------------
__global__ __launch_bounds__(256) void prep_all(
    const float* __restrict__ inp, const float* __restrict__ hx,
    const float* __restrict__ gwh,
    const float* __restrict__ Wq2, const float* __restrict__ Wk2, const float* __restrict__ Wv2,
    const float* __restrict__ gate_w, const float* __restrict__ fc_w,
    const float* __restrict__ Wq1, const float* __restrict__ Wk1,
    unsigned short* __restrict__ inp_bf, unsigned short* __restrict__ hx_bf,
    unsigned short* __restrict__ whp,    // [8][384'][128]
    unsigned short* __restrict__ w2_t,   // [8][192][128]
    unsigned short* __restrict__ gfc_t,  // [2][128][64]
    unsigned short* __restrict__ wq1t_hi, unsigned short* __restrict__ wq1t_lo, // [8][64][128]
    unsigned short* __restrict__ wk1t_hi, unsigned short* __restrict__ wk1t_lo) // [64][256]
{
    int idx = blockIdx.x * 256 + threadIdx.x;
    if (idx < 524288) {            // inp cast, 4 f32/thread
        float4 v = *(const float4*)(inp + (size_t)idx * 4);
        uint2 u;
        u.x = (unsigned)f2bf(v.x) | ((unsigned)f2bf(v.y) << 16);
        u.y = (unsigned)f2bf(v.z) | ((unsigned)f2bf(v.w) << 16);
        *(uint2*)(inp_bf + (size_t)idx * 4) = u; return;
    }
    idx -= 524288;
    if (idx < 2097152) {           // hx cast
        float4 v = *(const float4*)(hx + (size_t)idx * 4);
        uint2 u;
        u.x = (unsigned)f2bf(v.x) | ((unsigned)f2bf(v.y) << 16);
        u.y = (unsigned)f2bf(v.z) | ((unsigned)f2bf(v.w) << 16);
        *(uint2*)(hx_bf + (size_t)idx * 4) = u; return;
    }
    idx -= 2097152;
    if (idx < 393216) {            // whp[k][c'][d] = gwh[k][d][j(c')]
        int k = idx / 49152, rem = idx % 49152, cp = rem / 128, d = rem % 128;
        int b2 = cp / 192, r2 = cp % 192, g = r2 / 64, jjl = r2 % 64;
        int j = g * 128 + b2 * 64 + jjl;
        whp[idx] = f2bf(gwh[((size_t)k * 128 + d) * 384 + j]); return;
    }
    idx -= 393216;
    if (idx < 196608) {            // w2_t[k][n][d] (q|k|v)
        int k = idx / 24576, r = idx % 24576, n = r / 128, d = r % 128;
        const float* Wsrc = (n < 64) ? Wq2 : ((n < 128) ? Wk2 : Wv2);
        w2_t[idx] = f2bf(Wsrc[((size_t)k * 128 + d) * 64 + (n & 63)]); return;
    }
    idx -= 196608;
    if (idx < 16384) {             // gfc_t[g][j][d]
        int g = idx / 8192, r = idx % 8192, j = r / 64, d = r % 64;
        gfc_t[idx] = f2bf((g ? fc_w : gate_w)[d * 128 + j]); return;
    }
    idx -= 16384;
    if (idx < 65536) {             // wq1t hi/lo [k][e][d] = Wq1[k][d][e]
        int k = idx / 8192, rem = idx % 8192, e = rem / 128, d = rem % 128;
        float s = Wq1[((size_t)k * 128 + d) * 64 + e];
        unsigned short h = f2bf(s);
        wq1t_hi[idx] = h; wq1t_lo[idx] = f2bf(s - bf2f(h)); return;
    }
    idx -= 65536;
    if (idx < 16384) {             // wk1t hi/lo [e][d] = Wk1[1][d][e]
        int e = idx / 256, d = idx % 256;
        float s = Wk1[16384 + d * 64 + e];
        unsigned short h = f2bf(s);
        wk1t_hi[idx] = h; wk1t_lo[idx] = f2bf(s - bf2f(h));
    }
}

// ---------------------------------------------------------------------------
// Score GEMM, hi/lo-split bf16 MFMA (~f32 accuracy, 4 terms).
// z<8: qbuf[b][z][e] = hx[b, z*128:]@Wq1[z]  (K=128); z==8: kk1 = inp@Wk1[1] (K=256).
// ---------------------------------------------------------------------------
__global__ __launch_bounds__(256) void gemm_score(
    const float* __restrict__ inp, const float* __restrict__ hx,
    const unsigned short* __restrict__ wq1t_hi, const unsigned short* __restrict__ wq1t_lo,
    const unsigned short* __restrict__ wk1t_hi, const unsigned short* __restrict__ wk1t_lo,
    float* __restrict__ qbuff, float* __restrict__ kk1f)
{
    __shared__ unsigned short AsH[64][72], AsL[64][72], BsH[64][72], BsL[64][72];
    const int tid = threadIdx.x;
    const int wave = tid >> 6, lane = tid & 63;
    const int wr = wave >> 1, wc = wave & 1;
    const int lr = lane & 15, lo = lane >> 4;
    const int rowBase = blockIdx.y * 64;
    const int z = blockIdx.z;
    const int K   = (z == 8) ? 256 : 128;
    const float* A = (z == 8) ? inp : hx;
    const int lda  = (z == 8) ? 256 : 1024;
    const int coff = (z == 8) ? 0 : z * 128;
    const unsigned short* Bh = (z == 8) ? wk1t_hi : wq1t_hi + z * 8192;
    const unsigned short* Bl = (z == 8) ? wk1t_lo : wq1t_lo + z * 8192;
    const int ldb = K;

    const f32x4 zero = {0.f,0.f,0.f,0.f};
    f32x4 acc[2][2]; acc[0][0]=zero; acc[0][1]=zero; acc[1][0]=zero; acc[1][1]=zero;

    for (int k0 = 0; k0 < K; k0 += 64) {
#pragma unroll
        for (int i = 0; i < 4; ++i) {
            int c = i*256 + tid; int r = c >> 4, kc = (c & 15) << 2;
            float4 v = *(const float4*)(A + (size_t)(rowBase + r) * lda + coff + k0 + kc);
            unsigned short h0=f2bf(v.x), h1=f2bf(v.y), h2=f2bf(v.z), h3=f2bf(v.w);
            AsH[r][kc]=h0; AsH[r][kc+1]=h1; AsH[r][kc+2]=h2; AsH[r][kc+3]=h3;
            AsL[r][kc]  =f2bf(v.x - bf2f(h0)); AsL[r][kc+1]=f2bf(v.y - bf2f(h1));
            AsL[r][kc+2]=f2bf(v.z - bf2f(h2)); AsL[r][kc+3]=f2bf(v.w - bf2f(h3));
        }
#pragma unroll
        for (int i = 0; i < 2; ++i) {
            int c = i*256 + tid; int n = c >> 3, kc = (c & 7) << 3;
            *(uint4*)&BsH[n][kc] = *(const uint4*)(Bh + (size_t)n * ldb + k0 + kc);
            *(uint4*)&BsL[n][kc] = *(const uint4*)(Bl + (size_t)n * ldb + k0 + kc);
        }
        __syncthreads();
#pragma unroll
        for (int ks = 0; ks < 64; ks += 32) {
            bf16x8 aH[2], aL[2], bH[2], bL[2];
            aH[0] = *(const bf16x8*)&AsH[wr*32 + lr][ks + lo*8];
            aH[1] = *(const bf16x8*)&AsH[wr*32 + 16 + lr][ks + lo*8];
            aL[0] = *(const bf16x8*)&AsL[wr*32 + lr][ks + lo*8];
            aL[1] = *(const bf16x8*)&AsL[wr*32 + 16 + lr][ks + lo*8];
            bH[0] = *(const bf16x8*)&BsH[wc*32 + lr][ks + lo*8];
            bH[1] = *(const bf16x8*)&BsH[wc*32 + 16 + lr][ks + lo*8];
            bL[0] = *(const bf16x8*)&BsL[wc*32 + lr][ks + lo*8];
            bL[1] = *(const bf16x8*)&BsL[wc*32 + 16 + lr][ks + lo*8];
#pragma unroll
            for (int i = 0; i < 2; ++i)
#pragma unroll
            for (int j = 0; j < 2; ++j) {
                acc[i][j] = MFMA16(aH[i], bH[j], acc[i][j]);
                acc[i][j] = MFMA16(aH[i], bL[j], acc[i][j]);
                acc[i][j] = MFMA16(aL[i], bH[j], acc[i][j]);
                acc[i][j] = MFMA16(aL[i], bL[j], acc[i][j]);
            }
        }
        __syncthreads();
    }
#pragma unroll
    for (int i = 0; i < 2; ++i)
#pragma unroll
    for (int jf = 0; jf < 2; ++jf)
#pragma unroll
    for (int r4 = 0; r4 < 4; ++r4) {
        int row = rowBase + wr*32 + i*16 + lo*4 + r4;
        int col = wc*32 + jf*16 + lr;
        float v = acc[i][jf][r4];
        if (z == 8) kk1f[(size_t)row * 64 + col] = v;
        else        qbuff[(size_t)row * 512 + z * 64 + col] = v;
    }
}

// ---------------------------------------------------------------------------
// Score + mask (f64 dot of f32 inputs), unchanged semantics.
// ---------------------------------------------------------------------------
__global__ __launch_bounds__(256) void score_mask_k(
    const float* __restrict__ qbuf, const float* __restrict__ kk1,
    float* __restrict__ cbuf, float* __restrict__ maskb)
{
    const int b = blockIdx.x * 256 + threadIdx.x;
    const float* kr = kk1 + (size_t)b * 64;
    double s[8];
#pragma unroll
    for (int k = 0; k < 8; ++k) {
        const float* qr = qbuf + (size_t)b * 512 + k * 64;
        double acc = 0.0;
#pragma unroll
        for (int d = 0; d < 64; ++d) acc = fma((double)qr[d], (double)kr[d], acc);
        s[k] = acc / 8.0;
    }
#pragma unroll
    for (int k = 0; k < 8; ++k) {
        int rank = 0;
#pragma unroll
        for (int j = 0; j < 8; ++j)
            rank += (s[j] < s[k]) || (s[j] == s[k] && j < k);
        maskb[(size_t)b * 8 + k] = (rank < 4) ? 0.f : 1.f;
        cbuf[(size_t)b * 8 + k] = (float)(1.0 / (1.0 + exp(-s[k])));
    }
}

// ---------------------------------------------------------------------------
// wcomb = Wv1[1] @ gwi[z]  (f32 inputs read directly, bf16 MFMA),
// written transposed + gate-permuted: wcp[z][c'][m].
// ---------------------------------------------------------------------------
__global__ __launch_bounds__(256) void gemm_wcomb(
    const float* __restrict__ Wv1, const float* __restrict__ gwi,
    unsigned short* __restrict__ wcp)
{
    __shared__ unsigned short As[64][72];
    __shared__ unsigned short Bs[64][72];
    const int tid = threadIdx.x;
    const int wave = tid >> 6, lane = tid & 63;
    const int wr = wave >> 1, wc = wave & 1;
    const int lr = lane & 15, lo = lane >> 4;
    const int rowBase = blockIdx.y * 64, colBase = blockIdx.x * 64;
    const int z = blockIdx.z;
    const float* A = Wv1 + 131072;             // [256][512]
    const float* B = gwi + (size_t)z * 196608; // [512][384]

    const f32x4 zero = {0.f,0.f,0.f,0.f};
    f32x4 acc[2][2]; acc[0][0]=zero; acc[0][1]=zero; acc[1][0]=zero; acc[1][1]=zero;

    for (int k0 = 0; k0 < 512; k0 += 64) {
#pragma unroll
        for (int i = 0; i < 4; ++i) {
            int c = i*256 + tid; int r = c >> 4, kc = (c & 15) << 2;
            float4 v = *(const float4*)(A + (size_t)(rowBase + r) * 512 + k0 + kc);
            unsigned short* p = &As[r][kc];
            p[0]=f2bf(v.x); p[1]=f2bf(v.y); p[2]=f2bf(v.z); p[3]=f2bf(v.w);
        }
#pragma unroll
        for (int i = 0; i < 4; ++i) {          // B row-major [K][N] -> Bs[n][k]
            int c = i*256 + tid; int kk = c >> 4, nc = (c & 15) << 2;
            float4 v = *(const float4*)(B + (size_t)(k0 + kk) * 384 + colBase + nc);
            Bs[nc+0][kk]=f2bf(v.x); Bs[nc+1][kk]=f2bf(v.y);
            Bs[nc+2][kk]=f2bf(v.z); Bs[nc+3][kk]=f2bf(v.w);
        }
        __syncthreads();
#pragma unroll
        for (int ks = 0; ks < 64; ks += 32) {
            bf16x8 a0 = *(const bf16x8*)&As[wr*32 + lr][ks + lo*8];
            bf16x8 a1 = *(const bf16x8*)&As[wr*32 + 16 + lr][ks + lo*8];
            bf16x8 b0 = *(const bf16x8*)&Bs[wc*32 + lr][ks + lo*8];
            bf16x8 b1 = *(const bf16x8*)&Bs[wc*32 + 16 + lr][ks + lo*8];
            acc[0][0] = MFMA16(a0,b0,acc[0][0]); acc[0][1] = MFMA16(a0,b1,acc[0][1]);
            acc[1][0] = MFMA16(a1,b0,acc[1][0]); acc[1][1] = MFMA16(a1,b1,acc[1][1]);
        }
        __syncthreads();
    }
#pragma unroll
    for (int i = 0; i < 2; ++i)
#pragma unroll
    for (int jf = 0; jf < 2; ++jf)
#pragma unroll
    for (int r4 = 0; r4 < 4; ++r4) {
        int row = rowBase + wr*32 + i*16 + lo*4 + r4;
        int n = colBase + wc*32 + jf*16 + lr;
        int g = n >> 7, jjf = n & 127;
        int c2 = (jjf >> 6) * 192 + g * 64 + (jjf & 63);
        wcp[(size_t)z*98304 + (size_t)c2*256 + row] = f2bf(acc[i][jf][r4]);
    }
}

// ---------------------------------------------------------------------------
// Fused GRU GEMM: phase1 x@wc (K=256, scaled by c at phase boundary) +
// phase2 h@wh (K=128), gate-interleaved B, GRU epilogue -> hxn bf16.
// grid (2, 128, 8); N=192/block (3 gates x 64 j).
// ---------------------------------------------------------------------------
__global__ __launch_bounds__(256) void gemm_gxh_fused(
    const unsigned short* __restrict__ inp_bf,  // [8192][256]
    const unsigned short* __restrict__ wcp,     // [8][384'][256]
    const unsigned short* __restrict__ hx_bf,   // [8192][1024]
    const unsigned short* __restrict__ whp,     // [8][384'][128]
    const float* __restrict__ cbuf,             // [8192][8]
    const float* __restrict__ gbi, const float* __restrict__ gbh,  // [8][384]
    const float* __restrict__ hx,               // [8192][1024] f32
    unsigned short* __restrict__ hxn)           // [8192][1024]
{
    __shared__ unsigned short As[64][72];
    __shared__ unsigned short Bs[192][72];
    const int tid = threadIdx.x;
    const int wave = tid >> 6, lane = tid & 63;
    const int wr = wave >> 1, wc = wave & 1;
    const int lr = lane & 15, lo = lane >> 4;
    const int b2 = blockIdx.x, j0 = b2 * 64;
    const int rowBase = blockIdx.y * 64;
    const int z = blockIdx.z;

    const f32x4 zero = {0.f,0.f,0.f,0.f};
    f32x4 arz[2][2][2], anx[2][2], anh[2][2];
#pragma unroll
    for (int g = 0; g < 2; ++g)
#pragma unroll
    for (int i = 0; i < 2; ++i)
#pragma unroll
    for (int j = 0; j < 2; ++j) arz[g][i][j] = zero;
#pragma unroll
    for (int i = 0; i < 2; ++i)
#pragma unroll
    for (int j = 0; j < 2; ++j) { anx[i][j] = zero; anh[i][j] = zero; }

    uint4 ra[2], rb[6];
    auto LOADT = [&](int t) {
#pragma unroll
        for (int i = 0; i < 2; ++i) {
            int c = i*256 + tid; int r = c >> 3, kc = (c & 7) << 3;
            const unsigned short* src = (t < 4)
                ? inp_bf + (size_t)(rowBase + r) * 256 + t*64 + kc
                : hx_bf + (size_t)(rowBase + r) * 1024 + z*128 + (t-4)*64 + kc;
            ra[i] = *(const uint4*)src;
        }
#pragma unroll
        for (int i = 0; i < 6; ++i) {
            int c = i*256 + tid; int n = c >> 3, kc = (c & 7) << 3;
            const unsigned short* src = (t < 4)
                ? wcp + (size_t)z*98304 + (size_t)(b2*192 + n) * 256 + t*64 + kc
                : whp + (size_t)z*49152 + (size_t)(b2*192 + n) * 128 + (t-4)*64 + kc;
            rb[i] = *(const uint4*)src;
        }
    };
    LOADT(0);
#pragma unroll
    for (int t = 0; t < 6; ++t) {
        __syncthreads();
#pragma unroll
        for (int i = 0; i < 2; ++i) { int c = i*256 + tid; *(uint4*)&As[c>>3][(c&7)<<3] = ra[i]; }
#pragma unroll
        for (int i = 0; i < 6; ++i) { int c = i*256 + tid; *(uint4*)&Bs[c>>3][(c&7)<<3] = rb[i]; }
        __syncthreads();
        if (t < 5) LOADT(t + 1);      // issue next-tile loads; latency hides under MFMA
#pragma unroll
        for (int ks = 0; ks < 64; ks += 32) {
            bf16x8 a0 = *(const bf16x8*)&As[wr*32 + lr][ks + lo*8];
            bf16x8 a1 = *(const bf16x8*)&As[wr*32 + 16 + lr][ks + lo*8];
#pragma unroll
            for (int g = 0; g < 3; ++g) {
                bf16x8 b0 = *(const bf16x8*)&Bs[g*64 + wc*32 + lr][ks + lo*8];
                bf16x8 b1 = *(const bf16x8*)&Bs[g*64 + wc*32 + 16 + lr][ks + lo*8];
                if (g < 2) {
                    arz[g][0][0] = MFMA16(a0,b0,arz[g][0][0]);
                    arz[g][0][1] = MFMA16(a0,b1,arz[g][0][1]);
                    arz[g][1][0] = MFMA16(a1,b0,arz[g][1][0]);
                    arz[g][1][1] = MFMA16(a1,b1,arz[g][1][1]);
                } else if (t < 4) {
                    anx[0][0] = MFMA16(a0,b0,anx[0][0]);
                    anx[0][1] = MFMA16(a0,b1,anx[0][1]);
                    anx[1][0] = MFMA16(a1,b0,anx[1][0]);
                    anx[1][1] = MFMA16(a1,b1,anx[1][1]);
                } else {
                    anh[0][0] = MFMA16(a0,b0,anh[0][0]);
                    anh[0][1] = MFMA16(a0,b1,anh[0][1]);
                    anh[1][0] = MFMA16(a1,b0,anh[1][0]);
                    anh[1][1] = MFMA16(a1,b1,anh[1][1]);
                }
            }
        }
        if (t == 3) {   // phase boundary: scale phase-1 sums by c[row]
#pragma unroll
            for (int i = 0; i < 2; ++i)
#pragma unroll
            for (int r4 = 0; r4 < 4; ++r4) {
                int row = rowBase + wr*32 + i*16 + lo*4 + r4;
                float cc = cbuf[(size_t)row * 8 + z];
                arz[0][i][0][r4] *= cc; arz[0][i][1][r4] *= cc;
                arz[1][i][0][r4] *= cc; arz[1][i][1][r4] *= cc;
                anx[i][0][r4] *= cc;    anx[i][1][r4] *= cc;
            }
        }
    }
    // GRU epilogue
    const float* bi = gbi + z * 384;
    const float* bh = gbh + z * 384;
#pragma unroll
    for (int i = 0; i < 2; ++i)
#pragma unroll
    for (int jf = 0; jf < 2; ++jf)
#pragma unroll
    for (int r4 = 0; r4 < 4; ++r4) {
        int row = rowBase + wr*32 + i*16 + lo*4 + r4;
        int jj = wc*32 + jf*16 + lr;
        int j = j0 + jj;
        float xr = arz[0][i][jf][r4] + bi[j]       + bh[j];
        float xz = arz[1][i][jf][r4] + bi[128 + j] + bh[128 + j];
        float xn = anx[i][jf][r4]    + bi[256 + j];
        float hn = anh[i][jf][r4]    + bh[256 + j];
        float r = sigmoidf_(xr), zz = sigmoidf_(xz);
        float n = tanhf(fmaf(r, hn, xn));
        float h = hx[(size_t)row * 1024 + z*128 + j];
        hxn[(size_t)row * 1024 + z*128 + j] = f2bf((1.f - zz) * n + zz * h);
    }
}

// ---------------------------------------------------------------------------
// qkv GEMM: q2|k2|v2 = hxn_z @ w2_t[z], N=192/block, same pipeline.
// ---------------------------------------------------------------------------
__global__ __launch_bounds__(256) void gemm_qkv(
    const unsigned short* __restrict__ hxn,    // [8192][1024]
    const unsigned short* __restrict__ w2_t,   // [8][192][128]
    unsigned short* __restrict__ qkv)          // [8192][8][192]
{
    __shared__ unsigned short As[64][72];
    __shared__ unsigned short Bs[192][72];
    const int tid = threadIdx.x;
    const int wave = tid >> 6, lane = tid & 63;
    const int wr = wave >> 1, wc = wave & 1;
    const int lr = lane & 15, lo = lane >> 4;
    const int rowBase = blockIdx.y * 64;
    const int z = blockIdx.z;

    const f32x4 zero = {0.f,0.f,0.f,0.f};
    f32x4 acc[3][2][2];
#pragma unroll
    for (int g = 0; g < 3; ++g)
#pragma unroll
    for (int i = 0; i < 2; ++i)
#pragma unroll
    for (int j = 0; j < 2; ++j) acc[g][i][j] = zero;

    uint4 ra[2], rb[6];
    auto LOADT = [&](int t) {
#pragma unroll
        for (int i = 0; i < 2; ++i) {
            int c = i*256 + tid; int r = c >> 3, kc = (c & 7) << 3;
            ra[i] = *(const uint4*)(hxn + (size_t)(rowBase + r) * 1024 + z*128 + t*64 + kc);
        }
#pragma unroll
        for (int i = 0; i < 6; ++i) {
            int c = i*256 + tid; int n = c >> 3, kc = (c & 7) << 3;
            rb[i] = *(const uint4*)(w2_t + (size_t)z*24576 + (size_t)n * 128 + t*64 + kc);
        }
    };
    LOADT(0);
#pragma unroll
    for (int t = 0; t < 2; ++t) {
        __syncthreads();
#pragma unroll
        for (int i = 0; i < 2; ++i) { int c = i*256 + tid; *(uint4*)&As[c>>3][(c&7)<<3] = ra[i]; }
#pragma unroll
        for (int i = 0; i < 6; ++i) { int c = i*256 + tid; *(uint4*)&Bs[c>>3][(c&7)<<3] = rb[i]; }
        __syncthreads();
        if (t < 1) LOADT(t + 1);
#pragma unroll
        for (int ks = 0; ks < 64; ks += 32) {
            bf16x8 a0 = *(const bf16x8*)&As[wr*32 + lr][ks + lo*8];
            bf16x8 a1 = *(const bf16x8*)&As[wr*32 + 16 + lr][ks + lo*8];
#pragma unroll
            for (int g = 0; g < 3; ++g) {
                bf16x8 b0 = *(const bf16x8*)&Bs[g*64 + wc*32 + lr][ks + lo*8];
                bf16x8 b1 = *(const bf16x8*)&Bs[g*64 + wc*32 + 16 + lr][ks + lo*8];
                acc[g][0][0] = MFMA16(a0,b0,acc[g][0][0]);
                acc[g][0][1] = MFMA16(a0,b1,acc[g][0][1]);
                acc[g][1][0] = MFMA16(a1,b0,acc[g][1][0]);
                acc[g][1][1] = MFMA16(a1,b1,acc[g][1][1]);
            }
        }
    }
#pragma unroll
    for (int g = 0; g < 3; ++g)
#pragma unroll
    for (int i = 0; i < 2; ++i)
#pragma unroll
    for (int jf = 0; jf < 2; ++jf)
#pragma unroll
    for (int r4 = 0; r4 < 4; ++r4) {
        int row = rowBase + wr*32 + i*16 + lo*4 + r4;
        int c = g*64 + wc*32 + jf*16 + lr;
        qkv[(size_t)row * 1536 + z*192 + c] = f2bf(acc[g][i][jf][r4]);
    }
}

// ---------------------------------------------------------------------------
// Second attention on bf16 qkv [8192][8][192], o bf16 [65536][64].
// ---------------------------------------------------------------------------
__global__ __launch_bounds__(256) void attn2_bf(
    const unsigned short* __restrict__ qkv, unsigned short* __restrict__ o)
{
    const int idx = blockIdx.x * 256 + threadIdx.x;  // < 8192*32
    const int qb = idx & 7, h = (idx >> 3) & 3, b = idx >> 5;
    const unsigned short* rowb = qkv + (size_t)b * 1536;
    float qv[16];
    ld8f(rowb + qb*192 + h*16, qv); ld8f(rowb + qb*192 + h*16 + 8, qv + 8);
    float sc[8]; float mx = -1e30f;
#pragma unroll
    for (int kb = 0; kb < 8; ++kb) {
        float kv[16];
        ld8f(rowb + kb*192 + 64 + h*16, kv); ld8f(rowb + kb*192 + 64 + h*16 + 8, kv + 8);
        float a = 0.f;
#pragma unroll
        for (int d = 0; d < 16; ++d) a = fmaf(qv[d], kv[d], a);
        sc[kb] = a * 0.25f;
        mx = fmaxf(mx, sc[kb]);
    }
    float sum = 0.f;
#pragma unroll
    for (int kb = 0; kb < 8; ++kb) { sc[kb] = expf(sc[kb] - mx); sum += sc[kb]; }
    const float inv = 1.f / sum;
    float oa[16];
#pragma unroll
    for (int d = 0; d < 16; ++d) oa[d] = 0.f;
#pragma unroll
    for (int kb = 0; kb < 8; ++kb) {
        float vv[16];
        ld8f(rowb + kb*192 + 128 + h*16, vv); ld8f(rowb + kb*192 + 128 + h*16 + 8, vv + 8);
#pragma unroll
        for (int d = 0; d < 16; ++d) oa[d] = fmaf(sc[kb], vv[d], oa[d]);
    }
    unsigned short t[16];
#pragma unroll
    for (int d = 0; d < 16; ++d) t[d] = f2bf(oa[d] * inv);
    uint4 u0, u1;
    u0.x = (unsigned)t[0] | ((unsigned)t[1]<<16);  u0.y = (unsigned)t[2] | ((unsigned)t[3]<<16);
    u0.z = (unsigned)t[4] | ((unsigned)t[5]<<16);  u0.w = (unsigned)t[6] | ((unsigned)t[7]<<16);
    u1.x = (unsigned)t[8] | ((unsigned)t[9]<<16);  u1.y = (unsigned)t[10]| ((unsigned)t[11]<<16);
    u1.z = (unsigned)t[12]| ((unsigned)t[13]<<16); u1.w = (unsigned)t[14]| ((unsigned)t[15]<<16);
    unsigned short* op = o + (size_t)(b*8 + qb) * 64 + h*16;
    *(uint4*)op = u0; *(uint4*)(op + 8) = u1;
}

// ---------------------------------------------------------------------------
// Fused gate/fc MFMA + epilogue + mask combine -> f32 outputs.
// ---------------------------------------------------------------------------
__global__ __launch_bounds__(256) void gatefc_final(
    const unsigned short* __restrict__ o,      // [65536][64]
    const unsigned short* __restrict__ gfc_t,  // [2][128][64]
    const float* __restrict__ gate_b, const float* __restrict__ fc_b,
    const unsigned short* __restrict__ hxn,    // [8192][1024] bf16
    const float* __restrict__ hx,              // [8192][1024] f32
    const float* __restrict__ maskb,           // [8192][8]
    float* __restrict__ out)
{
    __shared__ unsigned short As[64][72];
    __shared__ unsigned short Bg[64][72];
    __shared__ unsigned short Bf[64][72];
    const int tid = threadIdx.x;
    const int wave = tid >> 6, lane = tid & 63;
    const int wr = wave >> 1, wc = wave & 1;
    const int lr = lane & 15, lo = lane >> 4;
    const int rowBase = blockIdx.y * 64, colBase = blockIdx.x * 64;

#pragma unroll
    for (int i = 0; i < 2; ++i) {
        int c = i*256 + tid;
        int r = c >> 3, kc = (c & 7) << 3;
        *(uint4*)&As[r][kc] = *(const uint4*)(o + (size_t)(rowBase + r) * 64 + kc);
        *(uint4*)&Bg[r][kc] = *(const uint4*)(gfc_t + (size_t)(colBase + r) * 64 + kc);
        *(uint4*)&Bf[r][kc] = *(const uint4*)(gfc_t + 8192 + (size_t)(colBase + r) * 64 + kc);
    }
    __syncthreads();

    const f32x4 zero = {0.f,0.f,0.f,0.f};
    f32x4 ag[2][2], af[2][2];
    ag[0][0]=zero; ag[0][1]=zero; ag[1][0]=zero; ag[1][1]=zero;
    af[0][0]=zero; af[0][1]=zero; af[1][0]=zero; af[1][1]=zero;
#pragma unroll
    for (int ks = 0; ks < 64; ks += 32) {
        bf16x8 a0 = *(const bf16x8*)&As[wr*32 + lr][ks + lo*8];
        bf16x8 a1 = *(const bf16x8*)&As[wr*32 + 16 + lr][ks + lo*8];
        bf16x8 g0 = *(const bf16x8*)&Bg[wc*32 + lr][ks + lo*8];
        bf16x8 g1 = *(const bf16x8*)&Bg[wc*32 + 16 + lr][ks + lo*8];
        bf16x8 f0 = *(const bf16x8*)&Bf[wc*32 + lr][ks + lo*8];
        bf16x8 f1 = *(const bf16x8*)&Bf[wc*32 + 16 + lr][ks + lo*8];
        ag[0][0] = MFMA16(a0,g0,ag[0][0]); ag[0][1] = MFMA16(a0,g1,ag[0][1]);
        ag[1][0] = MFMA16(a1,g0,ag[1][0]); ag[1][1] = MFMA16(a1,g1,ag[1][1]);
        af[0][0] = MFMA16(a0,f0,af[0][0]); af[0][1] = MFMA16(a0,f1,af[0][1]);
        af[1][0] = MFMA16(a1,f0,af[1][0]); af[1][1] = MFMA16(a1,f1,af[1][1]);
    }
#pragma unroll
    for (int i = 0; i < 2; ++i)
#pragma unroll
    for (int jf = 0; jf < 2; ++jf)
#pragma unroll
    for (int r4 = 0; r4 < 4; ++r4) {
        int m   = rowBase + wr*32 + i*16 + lo*4 + r4;   // = b*8+qb
        int col = colBase + wc*32 + jf*16 + lr;
        float g = sigmoidf_(ag[i][jf][r4] + gate_b[col]);
        float f = tanhf(af[i][jf][r4] + fc_b[col]);
        float att = g * f;
        size_t oidx = (size_t)m * 128 + col;
        float msk = maskb[m];
        float hnv = bf2f(hxn[oidx]) + att;
        out[oidx] = msk * hnv + (1.f - msk) * hx[oidx];
        out[(size_t)NB * 1024 + oidx] = msk;
    }
}

// ---------------------------------------------------------------------------
extern "C" void kernel_launch(void* const* d_in, const int* in_sizes, int n_in,
                              void* d_out, int out_size, void* d_ws, size_t ws_size,
                              hipStream_t stream)
{
    (void)in_sizes; (void)n_in; (void)out_size; (void)ws_size;
    const float* inp    = (const float*)d_in[0];
    const float* hx     = (const float*)d_in[1];
    const float* Wq1    = (const float*)d_in[3];
    const float* Wk1    = (const float*)d_in[4];
    const float* Wv1    = (const float*)d_in[5];
    const float* Wq2    = (const float*)d_in[6];
    const float* Wk2    = (const float*)d_in[7];
    const float* Wv2    = (const float*)d_in[8];
    const float* fc_w   = (const float*)d_in[9];
    const float* fc_b   = (const float*)d_in[10];
    const float* gate_w = (const float*)d_in[11];
    const float* gate_b = (const float*)d_in[12];
    const float* gwi    = (const float*)d_in[13];
    const float* gwh    = (const float*)d_in[14];
    const float* gbi    = (const float*)d_in[15];
    const float* gbh    = (const float*)d_in[16];
    float* out = (float*)d_out;

    // ---- workspace arena (byte offsets; total ~94 MB) ----
    char* W = (char*)d_ws;
    float* cbuf  = (float*)(W + 0x0);
    float* maskb = (float*)(W + 0x40000);
    float* kk1f  = (float*)(W + 0x80000);
    float* qbuff = (float*)(W + 0x280000);
    unsigned short* inp_bf   = (unsigned short*)(W + 0x1280000);
    unsigned short* hx_bf    = (unsigned short*)(W + 0x1680000);
    unsigned short* whp      = (unsigned short*)(W + 0x2680000);
    unsigned short* w2_t     = (unsigned short*)(W + 0x2740000);
    unsigned short* gfc_t    = (unsigned short*)(W + 0x27A0000);
    unsigned short* wq1t_hi  = (unsigned short*)(W + 0x27A8000);
    unsigned short* wq1t_lo  = (unsigned short*)(W + 0x27C8000);
    unsigned short* wk1t_hi  = (unsigned short*)(W + 0x27E8000);
    unsigned short* wk1t_lo  = (unsigned short*)(W + 0x27F0000);
    unsigned short* wcp      = (unsigned short*)(W + 0x27F8000);
    unsigned short* hxn      = (unsigned short*)(W + 0x2978000);
    unsigned short* qkv      = (unsigned short*)(W + 0x3978000);
    unsigned short* o_bf     = (unsigned short*)(W + 0x5178000);

    const dim3 blk(256);

    // (1) wcomb = Wv1[1] @ gwi (reads f32 inputs directly)
    gemm_wcomb<<<dim3(6, 4, 8), blk, 0, stream>>>(Wv1, gwi, wcp);
    // (2) casts + weight prep (one launch)
    prep_all<<<dim3(12928), blk, 0, stream>>>(inp, hx, gwh, Wq2, Wk2, Wv2, gate_w, fc_w,
                                              Wq1, Wk1, inp_bf, hx_bf, whp, w2_t, gfc_t,
                                              wq1t_hi, wq1t_lo, wk1t_hi, wk1t_lo);
    // (3) score GEMM (hi/lo MFMA), then f64 dot + mask
    gemm_score<<<dim3(1, 128, 9), blk, 0, stream>>>(inp, hx, wq1t_hi, wq1t_lo,
                                                    wk1t_hi, wk1t_lo, qbuff, kk1f);
    score_mask_k<<<dim3(32), blk, 0, stream>>>(qbuff, kk1f, cbuf, maskb);
    // (4) fused GRU GEMM -> hxn
    gemm_gxh_fused<<<dim3(2, 128, 8), blk, 0, stream>>>(inp_bf, wcp, hx_bf, whp,
                                                        cbuf, gbi, gbh, hx, hxn);
    // (5) qkv GEMM
    gemm_qkv<<<dim3(1, 128, 8), blk, 0, stream>>>(hxn, w2_t, qkv);
    // (6) attention-2
    attn2_bf<<<dim3(1024), blk, 0, stream>>>(qkv, o_bf);
    // (7) gate/fc + mask combine -> f32 outputs
    gatefc_final<<<dim3(2, 1024), blk, 0, stream>>>(o_bf, gfc_t, gate_b, fc_b,
                                                    hxn, hx, maskb, out);
}

// Round 8
// 333.697 us; speedup vs baseline: 1.2468x; 1.2468x over previous
//
#include <hip/hip_runtime.h>
#include <cstdint>
#include <cstddef>

#define NB 8192
// NINP=256, NHID=1024, NB_OUT=8, BS_OUT=128, ATT_OUT=512

typedef __attribute__((ext_vector_type(4))) float f32x4;
typedef __attribute__((ext_vector_type(8))) short bf16x8;

__device__ __forceinline__ float sigmoidf_(float x){ return 1.0f/(1.0f+expf(-x)); }

__device__ __forceinline__ unsigned short f2bf(float f){
    union { float f; unsigned u; } v; v.f = f;
    unsigned u = v.u;
    return (unsigned short)((u + 0x7fffu + ((u >> 16) & 1u)) >> 16);
}
__device__ __forceinline__ float bf2f(unsigned short b){
    union { unsigned u; float f; } v; v.u = ((unsigned)b) << 16;
    return v.f;
}
__device__ __forceinline__ void ld8f(const unsigned short* p, float* f){
    uint4 u = *(const uint4*)p;
    f[0]=bf2f(u.x&0xffff); f[1]=bf2f(u.x>>16);
    f[2]=bf2f(u.y&0xffff); f[3]=bf2f(u.y>>16);
    f[4]=bf2f(u.z&0xffff); f[5]=bf2f(u.z>>16);
    f[6]=bf2f(u.w&0xffff); f[7]=bf2f(u.w>>16);
}
#define MFMA16(a,b,c) __builtin_amdgcn_mfma_f32_16x16x32_bf16(a,b,c,0,0,0)

// ---------------------------------------------------------------------------
// prep_all: casts + weight transposes/permutations. One launch.
// Gate-interleave permutation: orig col n in [0,384): g=n>>7, jj=n&127,
//   b2=jj>>6, c' = b2*192 + g*64 + (jj&63).
// ---------------------------------------------------------------------------
__global__ __launch_bounds__(256) void prep_all(
    const float* __restrict__ inp, const float* __restrict__ hx,
    const float* __restrict__ gwh,
    const float* __restrict__ Wq2, const float* __restrict__ Wk2, const float* __restrict__ Wv2,
    const float* __restrict__ gate_w, const float* __restrict__ fc_w,
    const float* __restrict__ Wq1, const float* __restrict__ Wk1,
    unsigned short* __restrict__ inp_bf, unsigned short* __restrict__ hx_bf,
    unsigned short* __restrict__ whp,    // [8][384'][128]
    unsigned short* __restrict__ w2_t,   // [8][192][128]
    unsigned short* __restrict__ gfc_t,  // [2][128][64]
    unsigned short* __restrict__ wq1t_hi, unsigned short* __restrict__ wq1t_lo, // [8][64][128]
    unsigned short* __restrict__ wk1t_hi, unsigned short* __restrict__ wk1t_lo) // [64][256]
{
    int idx = blockIdx.x * 256 + threadIdx.x;
    if (idx < 524288) {            // inp cast, 4 f32/thread
        float4 v = *(const float4*)(inp + (size_t)idx * 4);
        uint2 u;
        u.x = (unsigned)f2bf(v.x) | ((unsigned)f2bf(v.y) << 16);
        u.y = (unsigned)f2bf(v.z) | ((unsigned)f2bf(v.w) << 16);
        *(uint2*)(inp_bf + (size_t)idx * 4) = u; return;
    }
    idx -= 524288;
    if (idx < 2097152) {           // hx cast
        float4 v = *(const float4*)(hx + (size_t)idx * 4);
        uint2 u;
        u.x = (unsigned)f2bf(v.x) | ((unsigned)f2bf(v.y) << 16);
        u.y = (unsigned)f2bf(v.z) | ((unsigned)f2bf(v.w) << 16);
        *(uint2*)(hx_bf + (size_t)idx * 4) = u; return;
    }
    idx -= 2097152;
    if (idx < 393216) {            // whp[k][c'][d] = gwh[k][d][j(c')]
        int k = idx / 49152, rem = idx % 49152, cp = rem / 128, d = rem % 128;
        int b2 = cp / 192, r2 = cp % 192, g = r2 / 64, jjl = r2 % 64;
        int j = g * 128 + b2 * 64 + jjl;
        whp[idx] = f2bf(gwh[((size_t)k * 128 + d) * 384 + j]); return;
    }
    idx -= 393216;
    if (idx < 196608) {            // w2_t[k][n][d] (q|k|v)
        int k = idx / 24576, r = idx % 24576, n = r / 128, d = r % 128;
        const float* Wsrc = (n < 64) ? Wq2 : ((n < 128) ? Wk2 : Wv2);
        w2_t[idx] = f2bf(Wsrc[((size_t)k * 128 + d) * 64 + (n & 63)]); return;
    }
    idx -= 196608;
    if (idx < 16384) {             // gfc_t[g][j][d]
        int g = idx / 8192, r = idx % 8192, j = r / 64, d = r % 64;
        gfc_t[idx] = f2bf((g ? fc_w : gate_w)[d * 128 + j]); return;
    }
    idx -= 16384;
    if (idx < 65536) {             // wq1t hi/lo [k][e][d] = Wq1[k][d][e]
        int k = idx / 8192, rem = idx % 8192, e = rem / 128, d = rem % 128;
        float s = Wq1[((size_t)k * 128 + d) * 64 + e];
        unsigned short h = f2bf(s);
        wq1t_hi[idx] = h; wq1t_lo[idx] = f2bf(s - bf2f(h)); return;
    }
    idx -= 65536;
    if (idx < 16384) {             // wk1t hi/lo [e][d] = Wk1[1][d][e]
        int e = idx / 256, d = idx % 256;
        float s = Wk1[16384 + d * 64 + e];
        unsigned short h = f2bf(s);
        wk1t_hi[idx] = h; wk1t_lo[idx] = f2bf(s - bf2f(h));
    }
}

// ---------------------------------------------------------------------------
// Score GEMM, hi/lo-split bf16 MFMA (~f32 accuracy, 4 terms).
// z<8: qbuf[b][z][e] = hx[b, z*128:]@Wq1[z] (K=128); z==8: kk1 = inp@Wk1[1] (K=256).
// ---------------------------------------------------------------------------
__global__ __launch_bounds__(256) void gemm_score(
    const float* __restrict__ inp, const float* __restrict__ hx,
    const unsigned short* __restrict__ wq1t_hi, const unsigned short* __restrict__ wq1t_lo,
    const unsigned short* __restrict__ wk1t_hi, const unsigned short* __restrict__ wk1t_lo,
    float* __restrict__ qbuff, float* __restrict__ kk1f)
{
    __shared__ unsigned short AsH[64][72], AsL[64][72], BsH[64][72], BsL[64][72];
    const int tid = threadIdx.x;
    const int wave = tid >> 6, lane = tid & 63;
    const int wr = wave >> 1, wc = wave & 1;
    const int lr = lane & 15, lo = lane >> 4;
    const int rowBase = blockIdx.y * 64;
    const int z = blockIdx.z;
    const int K   = (z == 8) ? 256 : 128;
    const float* A = (z == 8) ? inp : hx;
    const int lda  = (z == 8) ? 256 : 1024;
    const int coff = (z == 8) ? 0 : z * 128;
    const unsigned short* Bh = (z == 8) ? wk1t_hi : wq1t_hi + z * 8192;
    const unsigned short* Bl = (z == 8) ? wk1t_lo : wq1t_lo + z * 8192;
    const int ldb = K;

    const f32x4 zero = {0.f,0.f,0.f,0.f};
    f32x4 acc[2][2]; acc[0][0]=zero; acc[0][1]=zero; acc[1][0]=zero; acc[1][1]=zero;

    for (int k0 = 0; k0 < K; k0 += 64) {
#pragma unroll
        for (int i = 0; i < 4; ++i) {
            int c = i*256 + tid; int r = c >> 4, kc = (c & 15) << 2;
            float4 v = *(const float4*)(A + (size_t)(rowBase + r) * lda + coff + k0 + kc);
            unsigned short h0=f2bf(v.x), h1=f2bf(v.y), h2=f2bf(v.z), h3=f2bf(v.w);
            AsH[r][kc]=h0; AsH[r][kc+1]=h1; AsH[r][kc+2]=h2; AsH[r][kc+3]=h3;
            AsL[r][kc]  =f2bf(v.x - bf2f(h0)); AsL[r][kc+1]=f2bf(v.y - bf2f(h1));
            AsL[r][kc+2]=f2bf(v.z - bf2f(h2)); AsL[r][kc+3]=f2bf(v.w - bf2f(h3));
        }
#pragma unroll
        for (int i = 0; i < 2; ++i) {
            int c = i*256 + tid; int n = c >> 3, kc = (c & 7) << 3;
            *(uint4*)&BsH[n][kc] = *(const uint4*)(Bh + (size_t)n * ldb + k0 + kc);
            *(uint4*)&BsL[n][kc] = *(const uint4*)(Bl + (size_t)n * ldb + k0 + kc);
        }
        __syncthreads();
#pragma unroll
        for (int ks = 0; ks < 64; ks += 32) {
            bf16x8 aH[2], aL[2], bH[2], bL[2];
            aH[0] = *(const bf16x8*)&AsH[wr*32 + lr][ks + lo*8];
            aH[1] = *(const bf16x8*)&AsH[wr*32 + 16 + lr][ks + lo*8];
            aL[0] = *(const bf16x8*)&AsL[wr*32 + lr][ks + lo*8];
            aL[1] = *(const bf16x8*)&AsL[wr*32 + 16 + lr][ks + lo*8];
            bH[0] = *(const bf16x8*)&BsH[wc*32 + lr][ks + lo*8];
            bH[1] = *(const bf16x8*)&BsH[wc*32 + 16 + lr][ks + lo*8];
            bL[0] = *(const bf16x8*)&BsL[wc*32 + lr][ks + lo*8];
            bL[1] = *(const bf16x8*)&BsL[wc*32 + 16 + lr][ks + lo*8];
#pragma unroll
            for (int i = 0; i < 2; ++i)
#pragma unroll
            for (int j = 0; j < 2; ++j) {
                acc[i][j] = MFMA16(aH[i], bH[j], acc[i][j]);
                acc[i][j] = MFMA16(aH[i], bL[j], acc[i][j]);
                acc[i][j] = MFMA16(aL[i], bH[j], acc[i][j]);
                acc[i][j] = MFMA16(aL[i], bL[j], acc[i][j]);
            }
        }
        __syncthreads();
    }
#pragma unroll
    for (int i = 0; i < 2; ++i)
#pragma unroll
    for (int jf = 0; jf < 2; ++jf)
#pragma unroll
    for (int r4 = 0; r4 < 4; ++r4) {
        int row = rowBase + wr*32 + i*16 + lo*4 + r4;
        int col = wc*32 + jf*16 + lr;
        float v = acc[i][jf][r4];
        if (z == 8) kk1f[(size_t)row * 64 + col] = v;
        else        qbuff[(size_t)row * 512 + z * 64 + col] = v;
    }
}

// ---------------------------------------------------------------------------
// Score + mask (f64 dot of f32 inputs).
// ---------------------------------------------------------------------------
__global__ __launch_bounds__(256) void score_mask_k(
    const float* __restrict__ qbuf, const float* __restrict__ kk1,
    float* __restrict__ cbuf, float* __restrict__ maskb)
{
    const int b = blockIdx.x * 256 + threadIdx.x;
    const float* kr = kk1 + (size_t)b * 64;
    double s[8];
#pragma unroll
    for (int k = 0; k < 8; ++k) {
        const float* qr = qbuf + (size_t)b * 512 + k * 64;
        double acc = 0.0;
#pragma unroll
        for (int d = 0; d < 64; ++d) acc = fma((double)qr[d], (double)kr[d], acc);
        s[k] = acc / 8.0;
    }
#pragma unroll
    for (int k = 0; k < 8; ++k) {
        int rank = 0;
#pragma unroll
        for (int j = 0; j < 8; ++j)
            rank += (s[j] < s[k]) || (s[j] == s[k] && j < k);
        maskb[(size_t)b * 8 + k] = (rank < 4) ? 0.f : 1.f;
        cbuf[(size_t)b * 8 + k] = (float)(1.0 / (1.0 + exp(-s[k])));
    }
}

// ---------------------------------------------------------------------------
// wcomb = Wv1[1] @ gwi[z], written transposed + gate-permuted: wcp[z][c'][m].
// ---------------------------------------------------------------------------
__global__ __launch_bounds__(256) void gemm_wcomb(
    const float* __restrict__ Wv1, const float* __restrict__ gwi,
    unsigned short* __restrict__ wcp)
{
    __shared__ unsigned short As[64][72];
    __shared__ unsigned short Bs[64][72];
    const int tid = threadIdx.x;
    const int wave = tid >> 6, lane = tid & 63;
    const int wr = wave >> 1, wc = wave & 1;
    const int lr = lane & 15, lo = lane >> 4;
    const int rowBase = blockIdx.y * 64, colBase = blockIdx.x * 64;
    const int z = blockIdx.z;
    const float* A = Wv1 + 131072;             // [256][512]
    const float* B = gwi + (size_t)z * 196608; // [512][384]

    const f32x4 zero = {0.f,0.f,0.f,0.f};
    f32x4 acc[2][2]; acc[0][0]=zero; acc[0][1]=zero; acc[1][0]=zero; acc[1][1]=zero;

    for (int k0 = 0; k0 < 512; k0 += 64) {
#pragma unroll
        for (int i = 0; i < 4; ++i) {
            int c = i*256 + tid; int r = c >> 4, kc = (c & 15) << 2;
            float4 v = *(const float4*)(A + (size_t)(rowBase + r) * 512 + k0 + kc);
            unsigned short* p = &As[r][kc];
            p[0]=f2bf(v.x); p[1]=f2bf(v.y); p[2]=f2bf(v.z); p[3]=f2bf(v.w);
        }
#pragma unroll
        for (int i = 0; i < 4; ++i) {          // B row-major [K][N] -> Bs[n][k]
            int c = i*256 + tid; int kk = c >> 4, nc = (c & 15) << 2;
            float4 v = *(const float4*)(B + (size_t)(k0 + kk) * 384 + colBase + nc);
            Bs[nc+0][kk]=f2bf(v.x); Bs[nc+1][kk]=f2bf(v.y);
            Bs[nc+2][kk]=f2bf(v.z); Bs[nc+3][kk]=f2bf(v.w);
        }
        __syncthreads();
#pragma unroll
        for (int ks = 0; ks < 64; ks += 32) {
            bf16x8 a0 = *(const bf16x8*)&As[wr*32 + lr][ks + lo*8];
            bf16x8 a1 = *(const bf16x8*)&As[wr*32 + 16 + lr][ks + lo*8];
            bf16x8 b0 = *(const bf16x8*)&Bs[wc*32 + lr][ks + lo*8];
            bf16x8 b1 = *(const bf16x8*)&Bs[wc*32 + 16 + lr][ks + lo*8];
            acc[0][0] = MFMA16(a0,b0,acc[0][0]); acc[0][1] = MFMA16(a0,b1,acc[0][1]);
            acc[1][0] = MFMA16(a1,b0,acc[1][0]); acc[1][1] = MFMA16(a1,b1,acc[1][1]);
        }
        __syncthreads();
    }
#pragma unroll
    for (int i = 0; i < 2; ++i)
#pragma unroll
    for (int jf = 0; jf < 2; ++jf)
#pragma unroll
    for (int r4 = 0; r4 < 4; ++r4) {
        int row = rowBase + wr*32 + i*16 + lo*4 + r4;
        int n = colBase + wc*32 + jf*16 + lr;
        int g = n >> 7, jjf = n & 127;
        int c2 = (jjf >> 6) * 192 + g * 64 + (jjf & 63);
        wcp[(size_t)z*98304 + (size_t)c2*256 + row] = f2bf(acc[i][jf][r4]);
    }
}

// ---------------------------------------------------------------------------
// Fused GRU GEMM (direct-LDS staging, no reg prefetch -> no spill):
// phase1 x@wc (K=256, c-scale at boundary) + phase2 h@wh (K=128),
// gate-interleaved B, GRU epilogue -> hxn bf16. grid (2, 128, 8).
// ---------------------------------------------------------------------------
__global__ __launch_bounds__(256) void gemm_gxh_fused(
    const unsigned short* __restrict__ inp_bf,  // [8192][256]
    const unsigned short* __restrict__ wcp,     // [8][384'][256]
    const unsigned short* __restrict__ hx_bf,   // [8192][1024]
    const unsigned short* __restrict__ whp,     // [8][384'][128]
    const float* __restrict__ cbuf,             // [8192][8]
    const float* __restrict__ gbi, const float* __restrict__ gbh,  // [8][384]
    const float* __restrict__ hx,               // [8192][1024] f32
    unsigned short* __restrict__ hxn)           // [8192][1024]
{
    __shared__ unsigned short As[64][72];
    __shared__ unsigned short Bs[192][72];
    const int tid = threadIdx.x;
    const int wave = tid >> 6, lane = tid & 63;
    const int wr = wave >> 1, wc = wave & 1;
    const int lr = lane & 15, lo = lane >> 4;
    const int b2 = blockIdx.x, j0 = b2 * 64;
    const int rowBase = blockIdx.y * 64;
    const int z = blockIdx.z;

    const f32x4 zero = {0.f,0.f,0.f,0.f};
    f32x4 arz[2][2][2], anx[2][2], anh[2][2];
#pragma unroll
    for (int g = 0; g < 2; ++g)
#pragma unroll
    for (int i = 0; i < 2; ++i)
#pragma unroll
    for (int j = 0; j < 2; ++j) arz[g][i][j] = zero;
#pragma unroll
    for (int i = 0; i < 2; ++i)
#pragma unroll
    for (int j = 0; j < 2; ++j) { anx[i][j] = zero; anh[i][j] = zero; }

#pragma unroll
    for (int t = 0; t < 6; ++t) {
        if (t) __syncthreads();
        // stage A tile (64 x 64)
#pragma unroll
        for (int i = 0; i < 2; ++i) {
            int c = i*256 + tid; int r = c >> 3, kc = (c & 7) << 3;
            const unsigned short* src = (t < 4)
                ? inp_bf + (size_t)(rowBase + r) * 256 + t*64 + kc
                : hx_bf + (size_t)(rowBase + r) * 1024 + z*128 + (t-4)*64 + kc;
            *(uint4*)&As[r][kc] = *(const uint4*)src;
        }
        // stage B tile (192 x 64)
#pragma unroll
        for (int i = 0; i < 6; ++i) {
            int c = i*256 + tid; int n = c >> 3, kc = (c & 7) << 3;
            const unsigned short* src = (t < 4)
                ? wcp + (size_t)z*98304 + (size_t)(b2*192 + n) * 256 + t*64 + kc
                : whp + (size_t)z*49152 + (size_t)(b2*192 + n) * 128 + (t-4)*64 + kc;
            *(uint4*)&Bs[n][kc] = *(const uint4*)src;
        }
        __syncthreads();
#pragma unroll
        for (int ks = 0; ks < 64; ks += 32) {
            bf16x8 a0 = *(const bf16x8*)&As[wr*32 + lr][ks + lo*8];
            bf16x8 a1 = *(const bf16x8*)&As[wr*32 + 16 + lr][ks + lo*8];
#pragma unroll
            for (int g = 0; g < 3; ++g) {
                bf16x8 b0 = *(const bf16x8*)&Bs[g*64 + wc*32 + lr][ks + lo*8];
                bf16x8 b1 = *(const bf16x8*)&Bs[g*64 + wc*32 + 16 + lr][ks + lo*8];
                if (g < 2) {
                    arz[g][0][0] = MFMA16(a0,b0,arz[g][0][0]);
                    arz[g][0][1] = MFMA16(a0,b1,arz[g][0][1]);
                    arz[g][1][0] = MFMA16(a1,b0,arz[g][1][0]);
                    arz[g][1][1] = MFMA16(a1,b1,arz[g][1][1]);
                } else if (t < 4) {
                    anx[0][0] = MFMA16(a0,b0,anx[0][0]);
                    anx[0][1] = MFMA16(a0,b1,anx[0][1]);
                    anx[1][0] = MFMA16(a1,b0,anx[1][0]);
                    anx[1][1] = MFMA16(a1,b1,anx[1][1]);
                } else {
                    anh[0][0] = MFMA16(a0,b0,anh[0][0]);
                    anh[0][1] = MFMA16(a0,b1,anh[0][1]);
                    anh[1][0] = MFMA16(a1,b0,anh[1][0]);
                    anh[1][1] = MFMA16(a1,b1,anh[1][1]);
                }
            }
        }
        if (t == 3) {   // phase boundary: scale phase-1 sums by c[row]
#pragma unroll
            for (int i = 0; i < 2; ++i)
#pragma unroll
            for (int r4 = 0; r4 < 4; ++r4) {
                int row = rowBase + wr*32 + i*16 + lo*4 + r4;
                float cc = cbuf[(size_t)row * 8 + z];
                arz[0][i][0][r4] *= cc; arz[0][i][1][r4] *= cc;
                arz[1][i][0][r4] *= cc; arz[1][i][1][r4] *= cc;
                anx[i][0][r4] *= cc;    anx[i][1][r4] *= cc;
            }
        }
    }
    // GRU epilogue
    const float* bi = gbi + z * 384;
    const float* bh = gbh + z * 384;
#pragma unroll
    for (int i = 0; i < 2; ++i)
#pragma unroll
    for (int jf = 0; jf < 2; ++jf)
#pragma unroll
    for (int r4 = 0; r4 < 4; ++r4) {
        int row = rowBase + wr*32 + i*16 + lo*4 + r4;
        int jj = wc*32 + jf*16 + lr;
        int j = j0 + jj;
        float xr = arz[0][i][jf][r4] + bi[j]       + bh[j];
        float xz = arz[1][i][jf][r4] + bi[128 + j] + bh[128 + j];
        float xn = anx[i][jf][r4]    + bi[256 + j];
        float hn = anh[i][jf][r4]    + bh[256 + j];
        float r = sigmoidf_(xr), zz = sigmoidf_(xz);
        float n = tanhf(fmaf(r, hn, xn));
        float h = hx[(size_t)row * 1024 + z*128 + j];
        hxn[(size_t)row * 1024 + z*128 + j] = f2bf((1.f - zz) * n + zz * h);
    }
}

// ---------------------------------------------------------------------------
// qkv GEMM: q2|k2|v2 = hxn_z @ w2_t[z], N=192/block, direct-LDS staging.
// ---------------------------------------------------------------------------
__global__ __launch_bounds__(256) void gemm_qkv(
    const unsigned short* __restrict__ hxn,    // [8192][1024]
    const unsigned short* __restrict__ w2_t,   // [8][192][128]
    unsigned short* __restrict__ qkv)          // [8192][8][192]
{
    __shared__ unsigned short As[64][72];
    __shared__ unsigned short Bs[192][72];
    const int tid = threadIdx.x;
    const int wave = tid >> 6, lane = tid & 63;
    const int wr = wave >> 1, wc = wave & 1;
    const int lr = lane & 15, lo = lane >> 4;
    const int rowBase = blockIdx.y * 64;
    const int z = blockIdx.z;

    const f32x4 zero = {0.f,0.f,0.f,0.f};
    f32x4 acc[3][2][2];
#pragma unroll
    for (int g = 0; g < 3; ++g)
#pragma unroll
    for (int i = 0; i < 2; ++i)
#pragma unroll
    for (int j = 0; j < 2; ++j) acc[g][i][j] = zero;

#pragma unroll
    for (int t = 0; t < 2; ++t) {
        if (t) __syncthreads();
#pragma unroll
        for (int i = 0; i < 2; ++i) {
            int c = i*256 + tid; int r = c >> 3, kc = (c & 7) << 3;
            *(uint4*)&As[r][kc] = *(const uint4*)(hxn + (size_t)(rowBase + r) * 1024 + z*128 + t*64 + kc);
        }
#pragma unroll
        for (int i = 0; i < 6; ++i) {
            int c = i*256 + tid; int n = c >> 3, kc = (c & 7) << 3;
            *(uint4*)&Bs[n][kc] = *(const uint4*)(w2_t + (size_t)z*24576 + (size_t)n * 128 + t*64 + kc);
        }
        __syncthreads();
#pragma unroll
        for (int ks = 0; ks < 64; ks += 32) {
            bf16x8 a0 = *(const bf16x8*)&As[wr*32 + lr][ks + lo*8];
            bf16x8 a1 = *(const bf16x8*)&As[wr*32 + 16 + lr][ks + lo*8];
#pragma unroll
            for (int g = 0; g < 3; ++g) {
                bf16x8 b0 = *(const bf16x8*)&Bs[g*64 + wc*32 + lr][ks + lo*8];
                bf16x8 b1 = *(const bf16x8*)&Bs[g*64 + wc*32 + 16 + lr][ks + lo*8];
                acc[g][0][0] = MFMA16(a0,b0,acc[g][0][0]);
                acc[g][0][1] = MFMA16(a0,b1,acc[g][0][1]);
                acc[g][1][0] = MFMA16(a1,b0,acc[g][1][0]);
                acc[g][1][1] = MFMA16(a1,b1,acc[g][1][1]);
            }
        }
    }
#pragma unroll
    for (int g = 0; g < 3; ++g)
#pragma unroll
    for (int i = 0; i < 2; ++i)
#pragma unroll
    for (int jf = 0; jf < 2; ++jf)
#pragma unroll
    for (int r4 = 0; r4 < 4; ++r4) {
        int row = rowBase + wr*32 + i*16 + lo*4 + r4;
        int c = g*64 + wc*32 + jf*16 + lr;
        qkv[(size_t)row * 1536 + z*192 + c] = f2bf(acc[g][i][jf][r4]);
    }
}

// ---------------------------------------------------------------------------
// Second attention on bf16 qkv [8192][8][192], o bf16 [65536][64].
// ---------------------------------------------------------------------------
__global__ __launch_bounds__(256) void attn2_bf(
    const unsigned short* __restrict__ qkv, unsigned short* __restrict__ o)
{
    const int idx = blockIdx.x * 256 + threadIdx.x;  // < 8192*32
    const int qb = idx & 7, h = (idx >> 3) & 3, b = idx >> 5;
    const unsigned short* rowb = qkv + (size_t)b * 1536;
    float qv[16];
    ld8f(rowb + qb*192 + h*16, qv); ld8f(rowb + qb*192 + h*16 + 8, qv + 8);
    float sc[8]; float mx = -1e30f;
#pragma unroll
    for (int kb = 0; kb < 8; ++kb) {
        float kv[16];
        ld8f(rowb + kb*192 + 64 + h*16, kv); ld8f(rowb + kb*192 + 64 + h*16 + 8, kv + 8);
        float a = 0.f;
#pragma unroll
        for (int d = 0; d < 16; ++d) a = fmaf(qv[d], kv[d], a);
        sc[kb] = a * 0.25f;
        mx = fmaxf(mx, sc[kb]);
    }
    float sum = 0.f;
#pragma unroll
    for (int kb = 0; kb < 8; ++kb) { sc[kb] = expf(sc[kb] - mx); sum += sc[kb]; }
    const float inv = 1.f / sum;
    float oa[16];
#pragma unroll
    for (int d = 0; d < 16; ++d) oa[d] = 0.f;
#pragma unroll
    for (int kb = 0; kb < 8; ++kb) {
        float vv[16];
        ld8f(rowb + kb*192 + 128 + h*16, vv); ld8f(rowb + kb*192 + 128 + h*16 + 8, vv + 8);
#pragma unroll
        for (int d = 0; d < 16; ++d) oa[d] = fmaf(sc[kb], vv[d], oa[d]);
    }
    unsigned short t[16];
#pragma unroll
    for (int d = 0; d < 16; ++d) t[d] = f2bf(oa[d] * inv);
    uint4 u0, u1;
    u0.x = (unsigned)t[0] | ((unsigned)t[1]<<16);  u0.y = (unsigned)t[2] | ((unsigned)t[3]<<16);
    u0.z = (unsigned)t[4] | ((unsigned)t[5]<<16);  u0.w = (unsigned)t[6] | ((unsigned)t[7]<<16);
    u1.x = (unsigned)t[8] | ((unsigned)t[9]<<16);  u1.y = (unsigned)t[10]| ((unsigned)t[11]<<16);
    u1.z = (unsigned)t[12]| ((unsigned)t[13]<<16); u1.w = (unsigned)t[14]| ((unsigned)t[15]<<16);
    unsigned short* op = o + (size_t)(b*8 + qb) * 64 + h*16;
    *(uint4*)op = u0; *(uint4*)(op + 8) = u1;
}

// ---------------------------------------------------------------------------
// Fused gate/fc MFMA + epilogue + mask combine -> f32 outputs.
// ---------------------------------------------------------------------------
__global__ __launch_bounds__(256) void gatefc_final(
    const unsigned short* __restrict__ o,      // [65536][64]
    const unsigned short* __restrict__ gfc_t,  // [2][128][64]
    const float* __restrict__ gate_b, const float* __restrict__ fc_b,
    const unsigned short* __restrict__ hxn,    // [8192][1024] bf16
    const float* __restrict__ hx,              // [8192][1024] f32
    const float* __restrict__ maskb,           // [8192][8]
    float* __restrict__ out)
{
    __shared__ unsigned short As[64][72];
    __shared__ unsigned short Bg[64][72];
    __shared__ unsigned short Bf[64][72];
    const int tid = threadIdx.x;
    const int wave = tid >> 6, lane = tid & 63;
    const int wr = wave >> 1, wc = wave & 1;
    const int lr = lane & 15, lo = lane >> 4;
    const int rowBase = blockIdx.y * 64, colBase = blockIdx.x * 64;

#pragma unroll
    for (int i = 0; i < 2; ++i) {
        int c = i*256 + tid;
        int r = c >> 3, kc = (c & 7) << 3;
        *(uint4*)&As[r][kc] = *(const uint4*)(o + (size_t)(rowBase + r) * 64 + kc);
        *(uint4*)&Bg[r][kc] = *(const uint4*)(gfc_t + (size_t)(colBase + r) * 64 + kc);
        *(uint4*)&Bf[r][kc] = *(const uint4*)(gfc_t + 8192 + (size_t)(colBase + r) * 64 + kc);
    }
    __syncthreads();

    const f32x4 zero = {0.f,0.f,0.f,0.f};
    f32x4 ag[2][2], af[2][2];
    ag[0][0]=zero; ag[0][1]=zero; ag[1][0]=zero; ag[1][1]=zero;
    af[0][0]=zero; af[0][1]=zero; af[1][0]=zero; af[1][1]=zero;
#pragma unroll
    for (int ks = 0; ks < 64; ks += 32) {
        bf16x8 a0 = *(const bf16x8*)&As[wr*32 + lr][ks + lo*8];
        bf16x8 a1 = *(const bf16x8*)&As[wr*32 + 16 + lr][ks + lo*8];
        bf16x8 g0 = *(const bf16x8*)&Bg[wc*32 + lr][ks + lo*8];
        bf16x8 g1 = *(const bf16x8*)&Bg[wc*32 + 16 + lr][ks + lo*8];
        bf16x8 f0 = *(const bf16x8*)&Bf[wc*32 + lr][ks + lo*8];
        bf16x8 f1 = *(const bf16x8*)&Bf[wc*32 + 16 + lr][ks + lo*8];
        ag[0][0] = MFMA16(a0,g0,ag[0][0]); ag[0][1] = MFMA16(a0,g1,ag[0][1]);
        ag[1][0] = MFMA16(a1,g0,ag[1][0]); ag[1][1] = MFMA16(a1,g1,ag[1][1]);
        af[0][0] = MFMA16(a0,f0,af[0][0]); af[0][1] = MFMA16(a0,f1,af[0][1]);
        af[1][0] = MFMA16(a1,f0,af[1][0]); af[1][1] = MFMA16(a1,f1,af[1][1]);
    }
#pragma unroll
    for (int i = 0; i < 2; ++i)
#pragma unroll
    for (int jf = 0; jf < 2; ++jf)
#pragma unroll
    for (int r4 = 0; r4 < 4; ++r4) {
        int m   = rowBase + wr*32 + i*16 + lo*4 + r4;   // = b*8+qb
        int col = colBase + wc*32 + jf*16 + lr;
        float g = sigmoidf_(ag[i][jf][r4] + gate_b[col]);
        float f = tanhf(af[i][jf][r4] + fc_b[col]);
        float att = g * f;
        size_t oidx = (size_t)m * 128 + col;
        float msk = maskb[m];
        float hnv = bf2f(hxn[oidx]) + att;
        out[oidx] = msk * hnv + (1.f - msk) * hx[oidx];
        out[(size_t)NB * 1024 + oidx] = msk;
    }
}

// ---------------------------------------------------------------------------
extern "C" void kernel_launch(void* const* d_in, const int* in_sizes, int n_in,
                              void* d_out, int out_size, void* d_ws, size_t ws_size,
                              hipStream_t stream)
{
    (void)in_sizes; (void)n_in; (void)out_size; (void)ws_size;
    const float* inp    = (const float*)d_in[0];
    const float* hx     = (const float*)d_in[1];
    const float* Wq1    = (const float*)d_in[3];
    const float* Wk1    = (const float*)d_in[4];
    const float* Wv1    = (const float*)d_in[5];
    const float* Wq2    = (const float*)d_in[6];
    const float* Wk2    = (const float*)d_in[7];
    const float* Wv2    = (const float*)d_in[8];
    const float* fc_w   = (const float*)d_in[9];
    const float* fc_b   = (const float*)d_in[10];
    const float* gate_w = (const float*)d_in[11];
    const float* gate_b = (const float*)d_in[12];
    const float* gwi    = (const float*)d_in[13];
    const float* gwh    = (const float*)d_in[14];
    const float* gbi    = (const float*)d_in[15];
    const float* gbh    = (const float*)d_in[16];
    float* out = (float*)d_out;

    // ---- workspace arena (byte offsets; total ~94 MB) ----
    char* W = (char*)d_ws;
    float* cbuf  = (float*)(W + 0x0);
    float* maskb = (float*)(W + 0x40000);
    float* kk1f  = (float*)(W + 0x80000);
    float* qbuff = (float*)(W + 0x280000);
    unsigned short* inp_bf   = (unsigned short*)(W + 0x1280000);
    unsigned short* hx_bf    = (unsigned short*)(W + 0x1680000);
    unsigned short* whp      = (unsigned short*)(W + 0x2680000);
    unsigned short* w2_t     = (unsigned short*)(W + 0x2740000);
    unsigned short* gfc_t    = (unsigned short*)(W + 0x27A0000);
    unsigned short* wq1t_hi  = (unsigned short*)(W + 0x27A8000);
    unsigned short* wq1t_lo  = (unsigned short*)(W + 0x27C8000);
    unsigned short* wk1t_hi  = (unsigned short*)(W + 0x27E8000);
    unsigned short* wk1t_lo  = (unsigned short*)(W + 0x27F0000);
    unsigned short* wcp      = (unsigned short*)(W + 0x27F8000);
    unsigned short* hxn      = (unsigned short*)(W + 0x2978000);
    unsigned short* qkv      = (unsigned short*)(W + 0x3978000);
    unsigned short* o_bf     = (unsigned short*)(W + 0x5178000);

    const dim3 blk(256);

    // (1) wcomb = Wv1[1] @ gwi (reads f32 inputs directly)
    gemm_wcomb<<<dim3(6, 4, 8), blk, 0, stream>>>(Wv1, gwi, wcp);
    // (2) casts + weight prep (one launch)
    prep_all<<<dim3(12928), blk, 0, stream>>>(inp, hx, gwh, Wq2, Wk2, Wv2, gate_w, fc_w,
                                              Wq1, Wk1, inp_bf, hx_bf, whp, w2_t, gfc_t,
                                              wq1t_hi, wq1t_lo, wk1t_hi, wk1t_lo);
    // (3) score GEMM (hi/lo MFMA), then f64 dot + mask
    gemm_score<<<dim3(1, 128, 9), blk, 0, stream>>>(inp, hx, wq1t_hi, wq1t_lo,
                                                    wk1t_hi, wk1t_lo, qbuff, kk1f);
    score_mask_k<<<dim3(32), blk, 0, stream>>>(qbuff, kk1f, cbuf, maskb);
    // (4) fused GRU GEMM -> hxn
    gemm_gxh_fused<<<dim3(2, 128, 8), blk, 0, stream>>>(inp_bf, wcp, hx_bf, whp,
                                                        cbuf, gbi, gbh, hx, hxn);
    // (5) qkv GEMM
    gemm_qkv<<<dim3(1, 128, 8), blk, 0, stream>>>(hxn, w2_t, qkv);
    // (6) attention-2
    attn2_bf<<<dim3(1024), blk, 0, stream>>>(qkv, o_bf);
    // (7) gate/fc + mask combine -> f32 outputs
    gatefc_final<<<dim3(2, 1024), blk, 0, stream>>>(o_bf, gfc_t, gate_b, fc_b,
                                                    hxn, hx, maskb, out);
}